// Round 1
// baseline (3003.736 us; speedup 1.0000x reference)
//
#include <hip/hip_runtime.h>
#include <hip/hip_bf16.h>
#include <math.h>

// ---------- types ----------
typedef __bf16 bf16_t;
typedef __bf16 bf16x8 __attribute__((ext_vector_type(8)));
typedef float  f32x4  __attribute__((ext_vector_type(4)));

#define D_FEAT 256
#define H_FEAT 512
#define LN_EPS 1e-5f

// ---------- kernel 1: weight prep (transpose + bf16) ----------
// W1t[n][k] = bf16(W1[k][n])  (H x H), W2t[c][k] = bf16(W2[k][c]) (D x H)
__global__ void wprep_kernel(const float* __restrict__ W1,
                             const float* __restrict__ W2,
                             bf16_t* __restrict__ W1t,
                             bf16_t* __restrict__ W2t) {
    int tid = blockIdx.x * blockDim.x + threadIdx.x;
    const int total1 = H_FEAT * H_FEAT;
    const int total2 = D_FEAT * H_FEAT;
    if (tid < total1) {
        int n = tid / H_FEAT, k = tid % H_FEAT;
        W1t[tid] = (bf16_t)W1[(long)k * H_FEAT + n];
    } else if (tid < total1 + total2) {
        int t = tid - total1;
        int c = t / H_FEAT, k = t % H_FEAT;
        W2t[t] = (bf16_t)W2[(long)k * D_FEAT + c];
    }
}

// ---------- kernel 2: scatter-add edges -> agg ----------
// one thread per 4 features of one edge
__global__ void scatter_kernel(const float* __restrict__ edge_attr,
                               const int* __restrict__ dst,
                               float* __restrict__ agg, int n_edges) {
    long tid = (long)blockIdx.x * blockDim.x + threadIdx.x;
    long total = (long)n_edges * 64;
    if (tid >= total) return;
    int e = (int)(tid >> 6);
    int q = ((int)tid & 63) << 2;
    int d = dst[e];
    const float4 v = *(const float4*)(edge_attr + (long)e * D_FEAT + q);
    float* p = agg + (long)d * D_FEAT + q;
    atomicAdd(p + 0, v.x);
    atomicAdd(p + 1, v.y);
    atomicAdd(p + 2, v.z);
    atomicAdd(p + 3, v.w);
}

// ---------- kernel 3: pack [x | agg] -> bf16 h_in ----------
// one thread per 8 elements of h_in
__global__ void pack_kernel(const float* __restrict__ x,
                            const float* __restrict__ agg,
                            bf16_t* __restrict__ h_in, int n_nodes) {
    int tid = blockIdx.x * blockDim.x + threadIdx.x;
    int total = n_nodes * (H_FEAT / 8);
    if (tid >= total) return;
    int row = tid >> 6;           // 64 chunks of 8 per row
    int c8 = (tid & 63) * 8;
    const float* src = (c8 < D_FEAT) ? (x + (long)row * D_FEAT + c8)
                                     : (agg + (long)row * D_FEAT + (c8 - D_FEAT));
    float4 v0 = *(const float4*)(src);
    float4 v1 = *(const float4*)(src + 4);
    bf16x8 o;
    o[0] = (bf16_t)v0.x; o[1] = (bf16_t)v0.y; o[2] = (bf16_t)v0.z; o[3] = (bf16_t)v0.w;
    o[4] = (bf16_t)v1.x; o[5] = (bf16_t)v1.y; o[6] = (bf16_t)v1.z; o[7] = (bf16_t)v1.w;
    *(bf16x8*)(h_in + (long)row * H_FEAT + c8) = o;
}

// ---------- kernel 4: GEMM1 + bias + SiLU -> act (bf16) ----------
// block = 4 waves (2x2), tile 128x128; per-wave 64x64 via 4x4 frags of 16x16x32
__global__ __launch_bounds__(256) void gemm1_kernel(
    const bf16_t* __restrict__ h_in, const bf16_t* __restrict__ W1t,
    const float* __restrict__ b1, bf16_t* __restrict__ act, int n_nodes) {
    int l = threadIdx.x & 63;
    int w = threadIdx.x >> 6;
    int wr = w >> 1, wc = w & 1;
    int rowbase = blockIdx.x * 128 + wr * 64;
    int colbase = blockIdx.y * 128 + wc * 64;
    int lr = l & 15;
    int ko = (l >> 4) * 8;

    f32x4 zero = {0.f, 0.f, 0.f, 0.f};
    f32x4 acc[4][4];
#pragma unroll
    for (int m = 0; m < 4; ++m)
#pragma unroll
        for (int n = 0; n < 4; ++n) acc[m][n] = zero;

    for (int k0 = 0; k0 < H_FEAT; k0 += 32) {
        bf16x8 a[4], b[4];
#pragma unroll
        for (int m = 0; m < 4; ++m) {
            int r = rowbase + m * 16 + lr;
            if (r >= n_nodes) r = 0;
            a[m] = *(const bf16x8*)(h_in + (long)r * H_FEAT + k0 + ko);
        }
#pragma unroll
        for (int n = 0; n < 4; ++n) {
            int c = colbase + n * 16 + lr;
            b[n] = *(const bf16x8*)(W1t + (long)c * H_FEAT + k0 + ko);
        }
#pragma unroll
        for (int m = 0; m < 4; ++m)
#pragma unroll
            for (int n = 0; n < 4; ++n)
                acc[m][n] = __builtin_amdgcn_mfma_f32_16x16x32_bf16(a[m], b[n], acc[m][n], 0, 0, 0);
    }

    int rg = (l >> 4) * 4;
#pragma unroll
    for (int m = 0; m < 4; ++m) {
#pragma unroll
        for (int i = 0; i < 4; ++i) {
            int r = rowbase + m * 16 + rg + i;
            if (r >= n_nodes) continue;
#pragma unroll
            for (int n = 0; n < 4; ++n) {
                int c = colbase + n * 16 + lr;
                float v = acc[m][n][i] + b1[c];
                v = v / (1.0f + __expf(-v));
                act[(long)r * H_FEAT + c] = (bf16_t)v;
            }
        }
    }
}

// ---------- kernel 5: GEMM2 + bias + LayerNorm + residual -> out (fp32) ----------
// block = 4 waves; each wave computes 16 rows x 256 cols (16 frags)
__global__ __launch_bounds__(256) void gemm2_ln_kernel(
    const bf16_t* __restrict__ act, const bf16_t* __restrict__ W2t,
    const float* __restrict__ b2, const float* __restrict__ gamma,
    const float* __restrict__ beta, const float* __restrict__ x,
    float* __restrict__ out, int n_nodes) {
    int l = threadIdx.x & 63;
    int w = threadIdx.x >> 6;
    int rowbase = blockIdx.x * 64 + w * 16;
    int lr = l & 15;
    int ko = (l >> 4) * 8;

    f32x4 zero = {0.f, 0.f, 0.f, 0.f};
    f32x4 acc[16];
#pragma unroll
    for (int n = 0; n < 16; ++n) acc[n] = zero;

    for (int k0 = 0; k0 < H_FEAT; k0 += 32) {
        int r = rowbase + lr;
        if (r >= n_nodes) r = 0;
        bf16x8 a = *(const bf16x8*)(act + (long)r * H_FEAT + k0 + ko);
#pragma unroll
        for (int n = 0; n < 16; ++n) {
            bf16x8 b = *(const bf16x8*)(W2t + (long)(n * 16 + lr) * H_FEAT + k0 + ko);
            acc[n] = __builtin_amdgcn_mfma_f32_16x16x32_bf16(a, b, acc[n], 0, 0, 0);
        }
    }

    // add bias b2 (h value before LN)
#pragma unroll
    for (int n = 0; n < 16; ++n) {
        int c = n * 16 + lr;
        float bb = b2[c];
#pragma unroll
        for (int i = 0; i < 4; ++i) acc[n][i] += bb;
    }

    // per-row stats: rows of this quarter-wave are 4*(l>>4)+i
    float s[4] = {0.f, 0.f, 0.f, 0.f};
    float q[4] = {0.f, 0.f, 0.f, 0.f};
#pragma unroll
    for (int n = 0; n < 16; ++n)
#pragma unroll
        for (int i = 0; i < 4; ++i) {
            float v = acc[n][i];
            s[i] += v;
            q[i] += v * v;
        }
#pragma unroll
    for (int m = 1; m < 16; m <<= 1) {
#pragma unroll
        for (int i = 0; i < 4; ++i) {
            s[i] += __shfl_xor(s[i], m);
            q[i] += __shfl_xor(q[i], m);
        }
    }
    float mu[4], rstd[4];
#pragma unroll
    for (int i = 0; i < 4; ++i) {
        mu[i] = s[i] * (1.0f / 256.0f);
        float var = q[i] * (1.0f / 256.0f) - mu[i] * mu[i];
        rstd[i] = rsqrtf(var + LN_EPS);
    }

    int rg = (l >> 4) * 4;
#pragma unroll
    for (int n = 0; n < 16; ++n) {
        int c = n * 16 + lr;
        float g = gamma[c], bt = beta[c];
#pragma unroll
        for (int i = 0; i < 4; ++i) {
            int r = rowbase + rg + i;
            if (r >= n_nodes) continue;
            float v = (acc[n][i] - mu[i]) * rstd[i] * g + bt + x[(long)r * D_FEAT + c];
            out[(long)r * D_FEAT + c] = v;
        }
    }
}

// ---------- launch ----------
extern "C" void kernel_launch(void* const* d_in, const int* in_sizes, int n_in,
                              void* d_out, int out_size, void* d_ws, size_t ws_size,
                              hipStream_t stream) {
    const float* x         = (const float*)d_in[0];
    const int*   edge_idx  = (const int*)d_in[1];   // row 0 = destinations
    const float* edge_attr = (const float*)d_in[2];
    const float* W1        = (const float*)d_in[3];
    const float* b1        = (const float*)d_in[4];
    const float* W2        = (const float*)d_in[5];
    const float* b2        = (const float*)d_in[6];
    const float* gamma     = (const float*)d_in[7];
    const float* beta      = (const float*)d_in[8];
    float* out = (float*)d_out;

    int n_nodes = in_sizes[0] / D_FEAT;
    int n_edges = in_sizes[2] / D_FEAT;

    // workspace layout (16B aligned)
    char* ws = (char*)d_ws;
    size_t off = 0;
    float*  agg  = (float*)(ws + off);  off += (size_t)n_nodes * D_FEAT * 4;   // 51.2 MB
    bf16_t* h_in = (bf16_t*)(ws + off); off += (size_t)n_nodes * H_FEAT * 2;   // 51.2 MB
    bf16_t* act  = (bf16_t*)(ws + off); off += (size_t)n_nodes * H_FEAT * 2;   // 51.2 MB
    bf16_t* W1t  = (bf16_t*)(ws + off); off += (size_t)H_FEAT * H_FEAT * 2;
    bf16_t* W2t  = (bf16_t*)(ws + off); off += (size_t)D_FEAT * H_FEAT * 2;

    // 0) zero agg
    hipMemsetAsync(agg, 0, (size_t)n_nodes * D_FEAT * 4, stream);

    // 1) weight prep
    {
        int total = H_FEAT * H_FEAT + D_FEAT * H_FEAT;
        wprep_kernel<<<(total + 255) / 256, 256, 0, stream>>>(W1, W2, W1t, W2t);
    }

    // 2) scatter-add
    {
        long total = (long)n_edges * 64;
        int blocks = (int)((total + 255) / 256);
        scatter_kernel<<<blocks, 256, 0, stream>>>(edge_attr, edge_idx, agg, n_edges);
    }

    // 3) pack
    {
        int total = n_nodes * (H_FEAT / 8);
        pack_kernel<<<(total + 255) / 256, 256, 0, stream>>>(x, agg, h_in, n_nodes);
    }

    // 4) GEMM1 + SiLU
    {
        dim3 grid((n_nodes + 127) / 128, H_FEAT / 128);
        gemm1_kernel<<<grid, 256, 0, stream>>>(h_in, W1t, b1, act, n_nodes);
    }

    // 5) GEMM2 + LN + residual
    {
        int blocks = (n_nodes + 63) / 64;
        gemm2_ln_kernel<<<blocks, 256, 0, stream>>>(act, W2t, b2, gamma, beta, x, out, n_nodes);
    }
}

// Round 2
// 664.774 us; speedup vs baseline: 4.5184x; 4.5184x over previous
//
#include <hip/hip_runtime.h>
#include <hip/hip_bf16.h>
#include <math.h>

// ---------- types ----------
typedef __bf16 bf16_t;
typedef __bf16 bf16x4 __attribute__((ext_vector_type(4)));
typedef __bf16 bf16x8 __attribute__((ext_vector_type(8)));
typedef float  f32x4  __attribute__((ext_vector_type(4)));

#define D_FEAT 256
#define H_FEAT 512
#define LN_EPS 1e-5f

// ---------- kernel 1: weight prep (transpose + bf16) ----------
__global__ void wprep_kernel(const float* __restrict__ W1,
                             const float* __restrict__ W2,
                             bf16_t* __restrict__ W1t,
                             bf16_t* __restrict__ W2t) {
    int tid = blockIdx.x * blockDim.x + threadIdx.x;
    const int total1 = H_FEAT * H_FEAT;
    const int total2 = D_FEAT * H_FEAT;
    if (tid < total1) {
        int n = tid / H_FEAT, k = tid % H_FEAT;
        W1t[tid] = (bf16_t)W1[(long)k * H_FEAT + n];
    } else if (tid < total1 + total2) {
        int t = tid - total1;
        int c = t / H_FEAT, k = t % H_FEAT;
        W2t[t] = (bf16_t)W2[(long)k * D_FEAT + c];
    }
}

// ---------- kernel 2a: histogram of destinations ----------
__global__ void hist_kernel(const int* __restrict__ dst, int* __restrict__ counts,
                            int n_edges) {
    int e = blockIdx.x * blockDim.x + threadIdx.x;
    if (e < n_edges) atomicAdd(&counts[dst[e]], 1);
}

// ---------- kernel 2b: single-block exclusive scan -> offsets, cursor ----------
__global__ __launch_bounds__(1024) void scan_kernel(const int* __restrict__ counts,
                                                    int* __restrict__ offsets,
                                                    int* __restrict__ cursor,
                                                    int n_nodes) {
    __shared__ int wsum[16];
    __shared__ int s_carry;
    int tid = threadIdx.x;
    int lane = tid & 63, wid = tid >> 6;
    if (tid == 0) s_carry = 0;
    __syncthreads();
    for (int base = 0; base < n_nodes; base += 1024) {
        int i = base + tid;
        int c = (i < n_nodes) ? counts[i] : 0;
        int v = c;
#pragma unroll
        for (int off = 1; off < 64; off <<= 1) {
            int t = __shfl_up(v, off);
            if (lane >= off) v += t;
        }
        if (lane == 63) wsum[wid] = v;
        __syncthreads();
        if (wid == 0) {
            int wv = (lane < 16) ? wsum[lane] : 0;
#pragma unroll
            for (int off = 1; off < 16; off <<= 1) {
                int t = __shfl_up(wv, off);
                if (lane >= off) wv += t;
            }
            if (lane < 16) wsum[lane] = wv;
        }
        __syncthreads();
        int waveoff = (wid > 0) ? wsum[wid - 1] : 0;
        int excl = s_carry + waveoff + v - c;
        if (i < n_nodes) { offsets[i] = excl; cursor[i] = excl; }
        __syncthreads();
        if (tid == 0) s_carry += wsum[15];
        __syncthreads();
    }
    if (tid == 0) offsets[n_nodes] = s_carry;
}

// ---------- kernel 2c: place edge ids into destination buckets ----------
__global__ void place_kernel(const int* __restrict__ dst, int* __restrict__ cursor,
                             int* __restrict__ sorted_eid, int n_edges) {
    int e = blockIdx.x * blockDim.x + threadIdx.x;
    if (e < n_edges) {
        int d = dst[e];
        int pos = atomicAdd(&cursor[d], 1);
        sorted_eid[pos] = e;
    }
}

// ---------- kernel 3: gather-sum + pack -> h_in (bf16 [x | agg]) ----------
// one wave per node
__global__ __launch_bounds__(256) void gather_kernel(
    const float* __restrict__ edge_attr, const int* __restrict__ sorted_eid,
    const int* __restrict__ offsets, const float* __restrict__ x,
    bf16_t* __restrict__ h_in, int n_nodes) {
    int node = (blockIdx.x * blockDim.x + threadIdx.x) >> 6;
    int lane = threadIdx.x & 63;
    if (node >= n_nodes) return;
    int s = offsets[node];
    int e = offsets[node + 1];

    f32x4 acc = {0.f, 0.f, 0.f, 0.f};
    for (int base = s; base < e; base += 64) {
        int cnt = e - base; if (cnt > 64) cnt = 64;
        int eid_l = (base + lane < e) ? sorted_eid[base + lane] : 0;
        for (int j = 0; j < cnt; ++j) {
            int eid = __shfl(eid_l, j);
            const f32x4 v = *(const f32x4*)(edge_attr + (long)eid * D_FEAT + lane * 4);
            acc += v;
        }
    }

    const f32x4 xv = *(const f32x4*)(x + (long)node * D_FEAT + lane * 4);
    bf16x4 ox, oa;
#pragma unroll
    for (int i = 0; i < 4; ++i) { ox[i] = (bf16_t)xv[i]; oa[i] = (bf16_t)acc[i]; }
    *(bf16x4*)(h_in + (long)node * H_FEAT + lane * 4) = ox;
    *(bf16x4*)(h_in + (long)node * H_FEAT + D_FEAT + lane * 4) = oa;
}

// ---------- kernel 4: GEMM1 + bias + SiLU -> act (bf16) ----------
__global__ __launch_bounds__(256) void gemm1_kernel(
    const bf16_t* __restrict__ h_in, const bf16_t* __restrict__ W1t,
    const float* __restrict__ b1, bf16_t* __restrict__ act, int n_nodes) {
    int l = threadIdx.x & 63;
    int w = threadIdx.x >> 6;
    int wr = w >> 1, wc = w & 1;
    int rowbase = blockIdx.x * 128 + wr * 64;
    int colbase = blockIdx.y * 128 + wc * 64;
    int lr = l & 15;
    int ko = (l >> 4) * 8;

    f32x4 zero = {0.f, 0.f, 0.f, 0.f};
    f32x4 acc[4][4];
#pragma unroll
    for (int m = 0; m < 4; ++m)
#pragma unroll
        for (int n = 0; n < 4; ++n) acc[m][n] = zero;

    for (int k0 = 0; k0 < H_FEAT; k0 += 32) {
        bf16x8 a[4], b[4];
#pragma unroll
        for (int m = 0; m < 4; ++m) {
            int r = rowbase + m * 16 + lr;
            if (r >= n_nodes) r = 0;
            a[m] = *(const bf16x8*)(h_in + (long)r * H_FEAT + k0 + ko);
        }
#pragma unroll
        for (int n = 0; n < 4; ++n) {
            int c = colbase + n * 16 + lr;
            b[n] = *(const bf16x8*)(W1t + (long)c * H_FEAT + k0 + ko);
        }
#pragma unroll
        for (int m = 0; m < 4; ++m)
#pragma unroll
            for (int n = 0; n < 4; ++n)
                acc[m][n] = __builtin_amdgcn_mfma_f32_16x16x32_bf16(a[m], b[n], acc[m][n], 0, 0, 0);
    }

    int rg = (l >> 4) * 4;
#pragma unroll
    for (int m = 0; m < 4; ++m) {
#pragma unroll
        for (int i = 0; i < 4; ++i) {
            int r = rowbase + m * 16 + rg + i;
            if (r >= n_nodes) continue;
#pragma unroll
            for (int n = 0; n < 4; ++n) {
                int c = colbase + n * 16 + lr;
                float v = acc[m][n][i] + b1[c];
                v = v / (1.0f + __expf(-v));
                act[(long)r * H_FEAT + c] = (bf16_t)v;
            }
        }
    }
}

// ---------- kernel 5: GEMM2 + bias + LayerNorm + residual -> out (fp32) ----------
__global__ __launch_bounds__(256) void gemm2_ln_kernel(
    const bf16_t* __restrict__ act, const bf16_t* __restrict__ W2t,
    const float* __restrict__ b2, const float* __restrict__ gamma,
    const float* __restrict__ beta, const float* __restrict__ x,
    float* __restrict__ out, int n_nodes) {
    int l = threadIdx.x & 63;
    int w = threadIdx.x >> 6;
    int rowbase = blockIdx.x * 64 + w * 16;
    int lr = l & 15;
    int ko = (l >> 4) * 8;

    f32x4 zero = {0.f, 0.f, 0.f, 0.f};
    f32x4 acc[16];
#pragma unroll
    for (int n = 0; n < 16; ++n) acc[n] = zero;

    for (int k0 = 0; k0 < H_FEAT; k0 += 32) {
        int r = rowbase + lr;
        if (r >= n_nodes) r = 0;
        bf16x8 a = *(const bf16x8*)(act + (long)r * H_FEAT + k0 + ko);
#pragma unroll
        for (int n = 0; n < 16; ++n) {
            bf16x8 b = *(const bf16x8*)(W2t + (long)(n * 16 + lr) * H_FEAT + k0 + ko);
            acc[n] = __builtin_amdgcn_mfma_f32_16x16x32_bf16(a, b, acc[n], 0, 0, 0);
        }
    }

#pragma unroll
    for (int n = 0; n < 16; ++n) {
        int c = n * 16 + lr;
        float bb = b2[c];
#pragma unroll
        for (int i = 0; i < 4; ++i) acc[n][i] += bb;
    }

    float s[4] = {0.f, 0.f, 0.f, 0.f};
    float q[4] = {0.f, 0.f, 0.f, 0.f};
#pragma unroll
    for (int n = 0; n < 16; ++n)
#pragma unroll
        for (int i = 0; i < 4; ++i) {
            float v = acc[n][i];
            s[i] += v;
            q[i] += v * v;
        }
#pragma unroll
    for (int m = 1; m < 16; m <<= 1) {
#pragma unroll
        for (int i = 0; i < 4; ++i) {
            s[i] += __shfl_xor(s[i], m);
            q[i] += __shfl_xor(q[i], m);
        }
    }
    float mu[4], rstd[4];
#pragma unroll
    for (int i = 0; i < 4; ++i) {
        mu[i] = s[i] * (1.0f / 256.0f);
        float var = q[i] * (1.0f / 256.0f) - mu[i] * mu[i];
        rstd[i] = rsqrtf(var + LN_EPS);
    }

    int rg = (l >> 4) * 4;
#pragma unroll
    for (int n = 0; n < 16; ++n) {
        int c = n * 16 + lr;
        float g = gamma[c], bt = beta[c];
#pragma unroll
        for (int i = 0; i < 4; ++i) {
            int r = rowbase + rg + i;
            if (r >= n_nodes) continue;
            float v = (acc[n][i] - mu[i]) * rstd[i] * g + bt + x[(long)r * D_FEAT + c];
            out[(long)r * D_FEAT + c] = v;
        }
    }
}

// ---------- launch ----------
extern "C" void kernel_launch(void* const* d_in, const int* in_sizes, int n_in,
                              void* d_out, int out_size, void* d_ws, size_t ws_size,
                              hipStream_t stream) {
    const float* x         = (const float*)d_in[0];
    const int*   edge_idx  = (const int*)d_in[1];   // row 0 = destinations
    const float* edge_attr = (const float*)d_in[2];
    const float* W1        = (const float*)d_in[3];
    const float* b1        = (const float*)d_in[4];
    const float* W2        = (const float*)d_in[5];
    const float* b2        = (const float*)d_in[6];
    const float* gamma     = (const float*)d_in[7];
    const float* beta      = (const float*)d_in[8];
    float* out = (float*)d_out;

    int n_nodes = in_sizes[0] / D_FEAT;
    int n_edges = in_sizes[2] / D_FEAT;

    // workspace layout (16B aligned)
    char* ws = (char*)d_ws;
    size_t off = 0;
    bf16_t* h_in   = (bf16_t*)(ws + off); off += (size_t)n_nodes * H_FEAT * 2;   // 51.2 MB
    bf16_t* act    = (bf16_t*)(ws + off); off += (size_t)n_nodes * H_FEAT * 2;   // 51.2 MB
    bf16_t* W1t    = (bf16_t*)(ws + off); off += (size_t)H_FEAT * H_FEAT * 2;
    bf16_t* W2t    = (bf16_t*)(ws + off); off += (size_t)D_FEAT * H_FEAT * 2;
    int* counts    = (int*)(ws + off);    off += (size_t)n_nodes * 4;
    int* offsets   = (int*)(ws + off);    off += (size_t)(n_nodes + 1) * 4;
    int* cursor    = (int*)(ws + off);    off += (size_t)n_nodes * 4;
    int* sorted_eid= (int*)(ws + off);    off += (size_t)n_edges * 4;

    // 0) zero counts
    hipMemsetAsync(counts, 0, (size_t)n_nodes * 4, stream);

    // 1) weight prep
    {
        int total = H_FEAT * H_FEAT + D_FEAT * H_FEAT;
        wprep_kernel<<<(total + 255) / 256, 256, 0, stream>>>(W1, W2, W1t, W2t);
    }

    // 2) CSR build: hist -> scan -> place
    hist_kernel<<<(n_edges + 255) / 256, 256, 0, stream>>>(edge_idx, counts, n_edges);
    scan_kernel<<<1, 1024, 0, stream>>>(counts, offsets, cursor, n_nodes);
    place_kernel<<<(n_edges + 255) / 256, 256, 0, stream>>>(edge_idx, cursor, sorted_eid, n_edges);

    // 3) gather-sum + pack
    {
        int blocks = (n_nodes * 64 + 255) / 256;
        gather_kernel<<<blocks, 256, 0, stream>>>(edge_attr, sorted_eid, offsets, x, h_in, n_nodes);
    }

    // 4) GEMM1 + SiLU
    {
        dim3 grid((n_nodes + 127) / 128, H_FEAT / 128);
        gemm1_kernel<<<grid, 256, 0, stream>>>(h_in, W1t, b1, act, n_nodes);
    }

    // 5) GEMM2 + LN + residual
    {
        int blocks = (n_nodes + 63) / 64;
        gemm2_ln_kernel<<<blocks, 256, 0, stream>>>(act, W2t, b2, gamma, beta, x, out, n_nodes);
    }
}

// Round 3
// 664.769 us; speedup vs baseline: 4.5185x; 1.0000x over previous
//
#include <hip/hip_runtime.h>
#include <hip/hip_bf16.h>
#include <math.h>

// ---------- types ----------
typedef __bf16 bf16_t;
typedef __bf16 bf16x4 __attribute__((ext_vector_type(4)));
typedef __bf16 bf16x8 __attribute__((ext_vector_type(8)));
typedef float  f32x4  __attribute__((ext_vector_type(4)));

#define D_FEAT 256
#define H_FEAT 512
#define LN_EPS 1e-5f

// ---------- kernel 1: weight prep (transpose + bf16) + zero counts ----------
// Replaces the pathological in-graph hipMemsetAsync node (485us for 200KB!).
__global__ void wprep_kernel(const float* __restrict__ W1,
                             const float* __restrict__ W2,
                             bf16_t* __restrict__ W1t,
                             bf16_t* __restrict__ W2t,
                             int* __restrict__ counts, int n_nodes) {
    int tid = blockIdx.x * blockDim.x + threadIdx.x;
    const int total1 = H_FEAT * H_FEAT;
    const int total2 = D_FEAT * H_FEAT;
    if (tid < n_nodes) counts[tid] = 0;
    if (tid < total1) {
        int n = tid / H_FEAT, k = tid % H_FEAT;
        W1t[tid] = (bf16_t)W1[(long)k * H_FEAT + n];
    } else if (tid < total1 + total2) {
        int t = tid - total1;
        int c = t / H_FEAT, k = t % H_FEAT;
        W2t[t] = (bf16_t)W2[(long)k * D_FEAT + c];
    }
}

// ---------- kernel 2a: histogram of destinations ----------
__global__ void hist_kernel(const int* __restrict__ dst, int* __restrict__ counts,
                            int n_edges) {
    int e = blockIdx.x * blockDim.x + threadIdx.x;
    if (e < n_edges) atomicAdd(&counts[dst[e]], 1);
}

// ---------- kernel 2b: single-block exclusive scan -> offsets, cursor ----------
__global__ __launch_bounds__(1024) void scan_kernel(const int* __restrict__ counts,
                                                    int* __restrict__ offsets,
                                                    int* __restrict__ cursor,
                                                    int n_nodes) {
    __shared__ int wsum[16];
    __shared__ int s_carry;
    int tid = threadIdx.x;
    int lane = tid & 63, wid = tid >> 6;
    if (tid == 0) s_carry = 0;
    __syncthreads();
    for (int base = 0; base < n_nodes; base += 1024) {
        int i = base + tid;
        int c = (i < n_nodes) ? counts[i] : 0;
        int v = c;
#pragma unroll
        for (int off = 1; off < 64; off <<= 1) {
            int t = __shfl_up(v, off);
            if (lane >= off) v += t;
        }
        if (lane == 63) wsum[wid] = v;
        __syncthreads();
        if (wid == 0) {
            int wv = (lane < 16) ? wsum[lane] : 0;
#pragma unroll
            for (int off = 1; off < 16; off <<= 1) {
                int t = __shfl_up(wv, off);
                if (lane >= off) wv += t;
            }
            if (lane < 16) wsum[lane] = wv;
        }
        __syncthreads();
        int waveoff = (wid > 0) ? wsum[wid - 1] : 0;
        int excl = s_carry + waveoff + v - c;
        if (i < n_nodes) { offsets[i] = excl; cursor[i] = excl; }
        __syncthreads();
        if (tid == 0) s_carry += wsum[15];
        __syncthreads();
    }
    if (tid == 0) offsets[n_nodes] = s_carry;
}

// ---------- kernel 2c: place edge ids into destination buckets ----------
__global__ void place_kernel(const int* __restrict__ dst, int* __restrict__ cursor,
                             int* __restrict__ sorted_eid, int n_edges) {
    int e = blockIdx.x * blockDim.x + threadIdx.x;
    if (e < n_edges) {
        int d = dst[e];
        int pos = atomicAdd(&cursor[d], 1);
        sorted_eid[pos] = e;
    }
}

// ---------- kernel 3: gather-sum + pack -> h_in (bf16 [x | agg]) ----------
// one wave per node
__global__ __launch_bounds__(256) void gather_kernel(
    const float* __restrict__ edge_attr, const int* __restrict__ sorted_eid,
    const int* __restrict__ offsets, const float* __restrict__ x,
    bf16_t* __restrict__ h_in, int n_nodes) {
    int node = (blockIdx.x * blockDim.x + threadIdx.x) >> 6;
    int lane = threadIdx.x & 63;
    if (node >= n_nodes) return;
    int s = offsets[node];
    int e = offsets[node + 1];

    f32x4 acc = {0.f, 0.f, 0.f, 0.f};
    for (int base = s; base < e; base += 64) {
        int cnt = e - base; if (cnt > 64) cnt = 64;
        int eid_l = (base + lane < e) ? sorted_eid[base + lane] : 0;
        for (int j = 0; j < cnt; ++j) {
            int eid = __shfl(eid_l, j);
            const f32x4 v = *(const f32x4*)(edge_attr + (long)eid * D_FEAT + lane * 4);
            acc += v;
        }
    }

    const f32x4 xv = *(const f32x4*)(x + (long)node * D_FEAT + lane * 4);
    bf16x4 ox, oa;
#pragma unroll
    for (int i = 0; i < 4; ++i) { ox[i] = (bf16_t)xv[i]; oa[i] = (bf16_t)acc[i]; }
    *(bf16x4*)(h_in + (long)node * H_FEAT + lane * 4) = ox;
    *(bf16x4*)(h_in + (long)node * H_FEAT + D_FEAT + lane * 4) = oa;
}

// ---------- kernel 4: GEMM1 + bias + SiLU -> act (bf16) ----------
__global__ __launch_bounds__(256) void gemm1_kernel(
    const bf16_t* __restrict__ h_in, const bf16_t* __restrict__ W1t,
    const float* __restrict__ b1, bf16_t* __restrict__ act, int n_nodes) {
    int l = threadIdx.x & 63;
    int w = threadIdx.x >> 6;
    int wr = w >> 1, wc = w & 1;
    int rowbase = blockIdx.x * 128 + wr * 64;
    int colbase = blockIdx.y * 128 + wc * 64;
    int lr = l & 15;
    int ko = (l >> 4) * 8;

    f32x4 zero = {0.f, 0.f, 0.f, 0.f};
    f32x4 acc[4][4];
#pragma unroll
    for (int m = 0; m < 4; ++m)
#pragma unroll
        for (int n = 0; n < 4; ++n) acc[m][n] = zero;

    for (int k0 = 0; k0 < H_FEAT; k0 += 32) {
        bf16x8 a[4], b[4];
#pragma unroll
        for (int m = 0; m < 4; ++m) {
            int r = rowbase + m * 16 + lr;
            if (r >= n_nodes) r = 0;
            a[m] = *(const bf16x8*)(h_in + (long)r * H_FEAT + k0 + ko);
        }
#pragma unroll
        for (int n = 0; n < 4; ++n) {
            int c = colbase + n * 16 + lr;
            b[n] = *(const bf16x8*)(W1t + (long)c * H_FEAT + k0 + ko);
        }
#pragma unroll
        for (int m = 0; m < 4; ++m)
#pragma unroll
            for (int n = 0; n < 4; ++n)
                acc[m][n] = __builtin_amdgcn_mfma_f32_16x16x32_bf16(a[m], b[n], acc[m][n], 0, 0, 0);
    }

    int rg = (l >> 4) * 4;
#pragma unroll
    for (int m = 0; m < 4; ++m) {
#pragma unroll
        for (int i = 0; i < 4; ++i) {
            int r = rowbase + m * 16 + rg + i;
            if (r >= n_nodes) continue;
#pragma unroll
            for (int n = 0; n < 4; ++n) {
                int c = colbase + n * 16 + lr;
                float v = acc[m][n][i] + b1[c];
                v = v / (1.0f + __expf(-v));
                act[(long)r * H_FEAT + c] = (bf16_t)v;
            }
        }
    }
}

// ---------- kernel 5: GEMM2 + bias + LayerNorm + residual -> out (fp32) ----------
__global__ __launch_bounds__(256) void gemm2_ln_kernel(
    const bf16_t* __restrict__ act, const bf16_t* __restrict__ W2t,
    const float* __restrict__ b2, const float* __restrict__ gamma,
    const float* __restrict__ beta, const float* __restrict__ x,
    float* __restrict__ out, int n_nodes) {
    int l = threadIdx.x & 63;
    int w = threadIdx.x >> 6;
    int rowbase = blockIdx.x * 64 + w * 16;
    int lr = l & 15;
    int ko = (l >> 4) * 8;

    f32x4 zero = {0.f, 0.f, 0.f, 0.f};
    f32x4 acc[16];
#pragma unroll
    for (int n = 0; n < 16; ++n) acc[n] = zero;

    for (int k0 = 0; k0 < H_FEAT; k0 += 32) {
        int r = rowbase + lr;
        if (r >= n_nodes) r = 0;
        bf16x8 a = *(const bf16x8*)(act + (long)r * H_FEAT + k0 + ko);
#pragma unroll
        for (int n = 0; n < 16; ++n) {
            bf16x8 b = *(const bf16x8*)(W2t + (long)(n * 16 + lr) * H_FEAT + k0 + ko);
            acc[n] = __builtin_amdgcn_mfma_f32_16x16x32_bf16(a, b, acc[n], 0, 0, 0);
        }
    }

#pragma unroll
    for (int n = 0; n < 16; ++n) {
        int c = n * 16 + lr;
        float bb = b2[c];
#pragma unroll
        for (int i = 0; i < 4; ++i) acc[n][i] += bb;
    }

    float s[4] = {0.f, 0.f, 0.f, 0.f};
    float q[4] = {0.f, 0.f, 0.f, 0.f};
#pragma unroll
    for (int n = 0; n < 16; ++n)
#pragma unroll
        for (int i = 0; i < 4; ++i) {
            float v = acc[n][i];
            s[i] += v;
            q[i] += v * v;
        }
#pragma unroll
    for (int m = 1; m < 16; m <<= 1) {
#pragma unroll
        for (int i = 0; i < 4; ++i) {
            s[i] += __shfl_xor(s[i], m);
            q[i] += __shfl_xor(q[i], m);
        }
    }
    float mu[4], rstd[4];
#pragma unroll
    for (int i = 0; i < 4; ++i) {
        mu[i] = s[i] * (1.0f / 256.0f);
        float var = q[i] * (1.0f / 256.0f) - mu[i] * mu[i];
        rstd[i] = rsqrtf(var + LN_EPS);
    }

    int rg = (l >> 4) * 4;
#pragma unroll
    for (int n = 0; n < 16; ++n) {
        int c = n * 16 + lr;
        float g = gamma[c], bt = beta[c];
#pragma unroll
        for (int i = 0; i < 4; ++i) {
            int r = rowbase + rg + i;
            if (r >= n_nodes) continue;
            float v = (acc[n][i] - mu[i]) * rstd[i] * g + bt + x[(long)r * D_FEAT + c];
            out[(long)r * D_FEAT + c] = v;
        }
    }
}

// ---------- launch ----------
extern "C" void kernel_launch(void* const* d_in, const int* in_sizes, int n_in,
                              void* d_out, int out_size, void* d_ws, size_t ws_size,
                              hipStream_t stream) {
    const float* x         = (const float*)d_in[0];
    const int*   edge_idx  = (const int*)d_in[1];   // row 0 = destinations
    const float* edge_attr = (const float*)d_in[2];
    const float* W1        = (const float*)d_in[3];
    const float* b1        = (const float*)d_in[4];
    const float* W2        = (const float*)d_in[5];
    const float* b2        = (const float*)d_in[6];
    const float* gamma     = (const float*)d_in[7];
    const float* beta      = (const float*)d_in[8];
    float* out = (float*)d_out;

    int n_nodes = in_sizes[0] / D_FEAT;
    int n_edges = in_sizes[2] / D_FEAT;

    // workspace layout (16B aligned)
    char* ws = (char*)d_ws;
    size_t off = 0;
    bf16_t* h_in   = (bf16_t*)(ws + off); off += (size_t)n_nodes * H_FEAT * 2;   // 51.2 MB
    bf16_t* act    = (bf16_t*)(ws + off); off += (size_t)n_nodes * H_FEAT * 2;   // 51.2 MB
    bf16_t* W1t    = (bf16_t*)(ws + off); off += (size_t)H_FEAT * H_FEAT * 2;
    bf16_t* W2t    = (bf16_t*)(ws + off); off += (size_t)D_FEAT * H_FEAT * 2;
    int* counts    = (int*)(ws + off);    off += (size_t)n_nodes * 4;
    int* offsets   = (int*)(ws + off);    off += (size_t)(n_nodes + 1) * 4;
    int* cursor    = (int*)(ws + off);    off += (size_t)n_nodes * 4;
    int* sorted_eid= (int*)(ws + off);    off += (size_t)n_edges * 4;

    // 1) weight prep + zero counts (no hipMemsetAsync — it cost ~485us in-graph)
    {
        int total = H_FEAT * H_FEAT + D_FEAT * H_FEAT;
        wprep_kernel<<<(total + 255) / 256, 256, 0, stream>>>(W1, W2, W1t, W2t,
                                                              counts, n_nodes);
    }

    // 2) CSR build: hist -> scan -> place
    hist_kernel<<<(n_edges + 255) / 256, 256, 0, stream>>>(edge_idx, counts, n_edges);
    scan_kernel<<<1, 1024, 0, stream>>>(counts, offsets, cursor, n_nodes);
    place_kernel<<<(n_edges + 255) / 256, 256, 0, stream>>>(edge_idx, cursor, sorted_eid, n_edges);

    // 3) gather-sum + pack
    {
        int blocks = (n_nodes * 64 + 255) / 256;
        gather_kernel<<<blocks, 256, 0, stream>>>(edge_attr, sorted_eid, offsets, x, h_in, n_nodes);
    }

    // 4) GEMM1 + SiLU
    {
        dim3 grid((n_nodes + 127) / 128, H_FEAT / 128);
        gemm1_kernel<<<grid, 256, 0, stream>>>(h_in, W1t, b1, act, n_nodes);
    }

    // 5) GEMM2 + LN + residual
    {
        int blocks = (n_nodes + 63) / 64;
        gemm2_ln_kernel<<<blocks, 256, 0, stream>>>(act, W2t, b2, gamma, beta, x, out, n_nodes);
    }
}

// Round 4
// 548.130 us; speedup vs baseline: 5.4800x; 1.2128x over previous
//
#include <hip/hip_runtime.h>
#include <hip/hip_bf16.h>
#include <math.h>
#include <stdint.h>

// ---------- types ----------
typedef __bf16 bf16_t;
typedef __bf16 bf16x4 __attribute__((ext_vector_type(4)));
typedef __bf16 bf16x8 __attribute__((ext_vector_type(8)));
typedef float  f32x4  __attribute__((ext_vector_type(4)));

#define D_FEAT 256
#define H_FEAT 512
#define LN_EPS 1e-5f

#define GLOBAL_AS __attribute__((address_space(1)))
#define LDS_AS    __attribute__((address_space(3)))

// ---------- kernel 1: weight prep (coalesced LDS-tile transpose + bf16) + zero counts ----------
// W1: 512x512 f32 -> W1t[n][k] bf16 (256 tiles of 32x32)
// W2: 512x256 f32 -> W2t[c][k] bf16 (128 tiles)
__global__ __launch_bounds__(256) void wprep_kernel(const float* __restrict__ W1,
                                                    const float* __restrict__ W2,
                                                    bf16_t* __restrict__ W1t,
                                                    bf16_t* __restrict__ W2t,
                                                    int* __restrict__ counts, int n_nodes) {
    __shared__ float tile[32][33];
    int b = blockIdx.x;
    int gtid = b * 256 + threadIdx.x;
    if (gtid < n_nodes) counts[gtid] = 0;

    int tx = threadIdx.x & 31, ty = threadIdx.x >> 5;  // 32 x 8
    if (b < 256) {  // W1 tiles: 16(k) x 16(n)
        int k0 = (b >> 4) * 32, n0 = (b & 15) * 32;
#pragma unroll
        for (int j = 0; j < 4; ++j)
            tile[ty * 4 + j][tx] = W1[(size_t)(k0 + ty * 4 + j) * H_FEAT + n0 + tx];
        __syncthreads();
#pragma unroll
        for (int j = 0; j < 4; ++j)
            W1t[(size_t)(n0 + ty * 4 + j) * H_FEAT + k0 + tx] = (bf16_t)tile[tx][ty * 4 + j];
    } else {        // W2 tiles: 16(k) x 8(n)
        int bb = b - 256;
        int k0 = (bb >> 3) * 32, n0 = (bb & 7) * 32;
#pragma unroll
        for (int j = 0; j < 4; ++j)
            tile[ty * 4 + j][tx] = W2[(size_t)(k0 + ty * 4 + j) * D_FEAT + n0 + tx];
        __syncthreads();
#pragma unroll
        for (int j = 0; j < 4; ++j)
            W2t[(size_t)(n0 + ty * 4 + j) * H_FEAT + k0 + tx] = (bf16_t)tile[tx][ty * 4 + j];
    }
}

// ---------- kernel 2a: histogram of destinations ----------
__global__ void hist_kernel(const int* __restrict__ dst, int* __restrict__ counts,
                            int n_edges) {
    int e = blockIdx.x * blockDim.x + threadIdx.x;
    if (e < n_edges) atomicAdd(&counts[dst[e]], 1);
}

// ---------- kernel 2b: 3-phase scan (replaces single-block serial scan) ----------
__global__ __launch_bounds__(1024) void scanA_kernel(const int* __restrict__ counts,
                                                     int* __restrict__ offsets,
                                                     int* __restrict__ blocksums,
                                                     int n_nodes) {
    __shared__ int wsum[16];
    int tid = threadIdx.x, lane = tid & 63, wid = tid >> 6;
    int i = blockIdx.x * 1024 + tid;
    int c = (i < n_nodes) ? counts[i] : 0;
    int v = c;
#pragma unroll
    for (int off = 1; off < 64; off <<= 1) {
        int t = __shfl_up(v, off);
        if (lane >= off) v += t;
    }
    if (lane == 63) wsum[wid] = v;
    __syncthreads();
    if (wid == 0) {
        int wv = (lane < 16) ? wsum[lane] : 0;
#pragma unroll
        for (int off = 1; off < 16; off <<= 1) {
            int t = __shfl_up(wv, off);
            if (lane >= off) wv += t;
        }
        if (lane < 16) wsum[lane] = wv;
    }
    __syncthreads();
    int waveoff = (wid > 0) ? wsum[wid - 1] : 0;
    if (i < n_nodes) offsets[i] = waveoff + v - c;       // block-local exclusive
    if (tid == 0) blocksums[blockIdx.x] = wsum[15];
}

// single wave scans block sums (requires nblocks <= 64; 50000/1024 = 49)
__global__ void scanB_kernel(const int* __restrict__ blocksums,
                             int* __restrict__ blockbase,
                             int* __restrict__ offsets, int nblocks, int n_nodes) {
    int lane = threadIdx.x;
    int c = (lane < nblocks) ? blocksums[lane] : 0;
    int v = c;
#pragma unroll
    for (int off = 1; off < 64; off <<= 1) {
        int t = __shfl_up(v, off);
        if (lane >= off) v += t;
    }
    if (lane < nblocks) blockbase[lane] = v - c;
    if (lane == 63) offsets[n_nodes] = v;
}

__global__ void scanC_kernel(int* __restrict__ offsets, int* __restrict__ cursor,
                             const int* __restrict__ blockbase, int n_nodes) {
    int i = blockIdx.x * blockDim.x + threadIdx.x;
    if (i < n_nodes) {
        int o = offsets[i] + blockbase[i >> 10];
        offsets[i] = o;
        cursor[i] = o;
    }
}

// ---------- kernel 2c: place edge ids into destination buckets ----------
__global__ void place_kernel(const int* __restrict__ dst, int* __restrict__ cursor,
                             int* __restrict__ sorted_eid, int n_edges) {
    int e = blockIdx.x * blockDim.x + threadIdx.x;
    if (e < n_edges) {
        int d = dst[e];
        int pos = atomicAdd(&cursor[d], 1);
        sorted_eid[pos] = e;
    }
}

// ---------- kernel 3: gather-sum + pack -> h_in (bf16 [x | agg]) ----------
__global__ __launch_bounds__(256) void gather_kernel(
    const float* __restrict__ edge_attr, const int* __restrict__ sorted_eid,
    const int* __restrict__ offsets, const float* __restrict__ x,
    bf16_t* __restrict__ h_in, int n_nodes) {
    int node = (blockIdx.x * blockDim.x + threadIdx.x) >> 6;
    int lane = threadIdx.x & 63;
    if (node >= n_nodes) return;
    int s = offsets[node];
    int e = offsets[node + 1];

    f32x4 acc = {0.f, 0.f, 0.f, 0.f};
    for (int base = s; base < e; base += 64) {
        int cnt = e - base; if (cnt > 64) cnt = 64;
        int eid_l = (base + lane < e) ? sorted_eid[base + lane] : 0;
        for (int j = 0; j < cnt; ++j) {
            int eid = __shfl(eid_l, j);
            const f32x4 v = *(const f32x4*)(edge_attr + (long)eid * D_FEAT + lane * 4);
            acc += v;
        }
    }

    const f32x4 xv = *(const f32x4*)(x + (long)node * D_FEAT + lane * 4);
    bf16x4 ox, oa;
#pragma unroll
    for (int i = 0; i < 4; ++i) { ox[i] = (bf16_t)xv[i]; oa[i] = (bf16_t)acc[i]; }
    *(bf16x4*)(h_in + (long)node * H_FEAT + lane * 4) = ox;
    *(bf16x4*)(h_in + (long)node * H_FEAT + D_FEAT + lane * 4) = oa;
}

// ---------- kernel 4: GEMM1 (m97 structure) + bias + SiLU -> act (bf16) ----------
// 128x128 tile, BK=32, 4 waves 2x2, double-buffered LDS via global_load_lds(16B).
// LDS layout per tile: [128 rows][4 slots of 16B]; slot swizzle s_lds = s_glob ^ ((row>>1)&3)
// (pre-swizzled global source, linear LDS dest, swizzled ds_read -> 2 lanes/bank = free).
__global__ __launch_bounds__(256) void gemm1_kernel(
    const bf16_t* __restrict__ h_in, const bf16_t* __restrict__ W1t,
    const float* __restrict__ b1, bf16_t* __restrict__ act, int n_nodes) {
    __shared__ bf16_t As[2][128 * 32];
    __shared__ bf16_t Bs[2][128 * 32];
    int l = threadIdx.x & 63;
    int w = threadIdx.x >> 6;
    int wr = w >> 1, wc = w & 1;
    int browbase = blockIdx.x * 128;
    int bcolbase = blockIdx.y * 128;
    int lr = l & 15;
    int sg = l >> 4;

    f32x4 zero = {0.f, 0.f, 0.f, 0.f};
    f32x4 acc[4][4];
#pragma unroll
    for (int m = 0; m < 4; ++m)
#pragma unroll
        for (int n = 0; n < 4; ++n) acc[m][n] = zero;

    auto stage = [&](int buf, int k0) {
#pragma unroll
        for (int q = 0; q < 2; ++q) {
            int lrow = w * 32 + q * 16 + (l >> 2);
            int ssrc = (l & 3) ^ ((lrow >> 1) & 3);
            // A
            int ga = browbase + lrow; if (ga >= n_nodes) ga = 0;
            const bf16_t* gA = h_in + (size_t)ga * H_FEAT + k0 + ssrc * 8;
            bf16_t* lA = &As[buf][(w * 32 + q * 16) * 32];  // wave-uniform base
            __builtin_amdgcn_global_load_lds((const GLOBAL_AS uint32_t*)gA,
                                             (LDS_AS uint32_t*)lA, 16, 0, 0);
            // B
            int gb = bcolbase + lrow;  // always < 512
            const bf16_t* gB = W1t + (size_t)gb * H_FEAT + k0 + ssrc * 8;
            bf16_t* lB = &Bs[buf][(w * 32 + q * 16) * 32];
            __builtin_amdgcn_global_load_lds((const GLOBAL_AS uint32_t*)gB,
                                             (LDS_AS uint32_t*)lB, 16, 0, 0);
        }
    };

    stage(0, 0);
    __syncthreads();
    int cur = 0;
    for (int t = 0; t < 16; ++t) {
        if (t < 15) stage(cur ^ 1, (t + 1) * 32);
        bf16x8 a[4], b[4];
#pragma unroll
        for (int m = 0; m < 4; ++m) {
            int row = wr * 64 + m * 16 + lr;
            int s = sg ^ ((row >> 1) & 3);
            a[m] = *(const bf16x8*)&As[cur][row * 32 + s * 8];
        }
#pragma unroll
        for (int n = 0; n < 4; ++n) {
            int col = wc * 64 + n * 16 + lr;
            int s = sg ^ ((col >> 1) & 3);
            b[n] = *(const bf16x8*)&Bs[cur][col * 32 + s * 8];
        }
#pragma unroll
        for (int m = 0; m < 4; ++m)
#pragma unroll
            for (int n = 0; n < 4; ++n)
                acc[m][n] = __builtin_amdgcn_mfma_f32_16x16x32_bf16(a[m], b[n], acc[m][n], 0, 0, 0);
        __syncthreads();
        cur ^= 1;
    }

    int rg = (l >> 4) * 4;
#pragma unroll
    for (int m = 0; m < 4; ++m) {
#pragma unroll
        for (int i = 0; i < 4; ++i) {
            int r = browbase + wr * 64 + m * 16 + rg + i;
            if (r >= n_nodes) continue;
#pragma unroll
            for (int n = 0; n < 4; ++n) {
                int c = bcolbase + wc * 64 + n * 16 + lr;
                float v = acc[m][n][i] + b1[c];
                v = v / (1.0f + __expf(-v));
                act[(long)r * H_FEAT + c] = (bf16_t)v;
            }
        }
    }
}

// ---------- kernel 5: GEMM2 + bias + LayerNorm + residual -> out (fp32) ----------
__global__ __launch_bounds__(256) void gemm2_ln_kernel(
    const bf16_t* __restrict__ act, const bf16_t* __restrict__ W2t,
    const float* __restrict__ b2, const float* __restrict__ gamma,
    const float* __restrict__ beta, const float* __restrict__ x,
    float* __restrict__ out, int n_nodes) {
    int l = threadIdx.x & 63;
    int w = threadIdx.x >> 6;
    int rowbase = blockIdx.x * 64 + w * 16;
    int lr = l & 15;
    int ko = (l >> 4) * 8;

    f32x4 zero = {0.f, 0.f, 0.f, 0.f};
    f32x4 acc[16];
#pragma unroll
    for (int n = 0; n < 16; ++n) acc[n] = zero;

    for (int k0 = 0; k0 < H_FEAT; k0 += 32) {
        int r = rowbase + lr;
        if (r >= n_nodes) r = 0;
        bf16x8 a = *(const bf16x8*)(act + (long)r * H_FEAT + k0 + ko);
#pragma unroll
        for (int n = 0; n < 16; ++n) {
            bf16x8 b = *(const bf16x8*)(W2t + (long)(n * 16 + lr) * H_FEAT + k0 + ko);
            acc[n] = __builtin_amdgcn_mfma_f32_16x16x32_bf16(a, b, acc[n], 0, 0, 0);
        }
    }

#pragma unroll
    for (int n = 0; n < 16; ++n) {
        int c = n * 16 + lr;
        float bb = b2[c];
#pragma unroll
        for (int i = 0; i < 4; ++i) acc[n][i] += bb;
    }

    float s[4] = {0.f, 0.f, 0.f, 0.f};
    float q[4] = {0.f, 0.f, 0.f, 0.f};
#pragma unroll
    for (int n = 0; n < 16; ++n)
#pragma unroll
        for (int i = 0; i < 4; ++i) {
            float v = acc[n][i];
            s[i] += v;
            q[i] += v * v;
        }
#pragma unroll
    for (int m = 1; m < 16; m <<= 1) {
#pragma unroll
        for (int i = 0; i < 4; ++i) {
            s[i] += __shfl_xor(s[i], m);
            q[i] += __shfl_xor(q[i], m);
        }
    }
    float mu[4], rstd[4];
#pragma unroll
    for (int i = 0; i < 4; ++i) {
        mu[i] = s[i] * (1.0f / 256.0f);
        float var = q[i] * (1.0f / 256.0f) - mu[i] * mu[i];
        rstd[i] = rsqrtf(var + LN_EPS);
    }

    int rg = (l >> 4) * 4;
#pragma unroll
    for (int n = 0; n < 16; ++n) {
        int c = n * 16 + lr;
        float g = gamma[c], bt = beta[c];
#pragma unroll
        for (int i = 0; i < 4; ++i) {
            int r = rowbase + rg + i;
            if (r >= n_nodes) continue;
            float v = (acc[n][i] - mu[i]) * rstd[i] * g + bt + x[(long)r * D_FEAT + c];
            out[(long)r * D_FEAT + c] = v;
        }
    }
}

// ---------- launch ----------
extern "C" void kernel_launch(void* const* d_in, const int* in_sizes, int n_in,
                              void* d_out, int out_size, void* d_ws, size_t ws_size,
                              hipStream_t stream) {
    const float* x         = (const float*)d_in[0];
    const int*   edge_idx  = (const int*)d_in[1];   // row 0 = destinations
    const float* edge_attr = (const float*)d_in[2];
    const float* W1        = (const float*)d_in[3];
    const float* b1        = (const float*)d_in[4];
    const float* W2        = (const float*)d_in[5];
    const float* b2        = (const float*)d_in[6];
    const float* gamma     = (const float*)d_in[7];
    const float* beta      = (const float*)d_in[8];
    float* out = (float*)d_out;

    int n_nodes = in_sizes[0] / D_FEAT;
    int n_edges = in_sizes[2] / D_FEAT;

    // workspace layout (16B aligned)
    char* ws = (char*)d_ws;
    size_t off = 0;
    bf16_t* h_in   = (bf16_t*)(ws + off); off += (size_t)n_nodes * H_FEAT * 2;
    bf16_t* act    = (bf16_t*)(ws + off); off += (size_t)n_nodes * H_FEAT * 2;
    bf16_t* W1t    = (bf16_t*)(ws + off); off += (size_t)H_FEAT * H_FEAT * 2;
    bf16_t* W2t    = (bf16_t*)(ws + off); off += (size_t)D_FEAT * H_FEAT * 2;
    int* counts    = (int*)(ws + off);    off += (size_t)n_nodes * 4;
    int* offsets   = (int*)(ws + off);    off += (size_t)(n_nodes + 1) * 4;
    int* cursor    = (int*)(ws + off);    off += (size_t)n_nodes * 4;
    int* sorted_eid= (int*)(ws + off);    off += (size_t)n_edges * 4;
    int* blocksums = (int*)(ws + off);    off += 64 * 4;
    int* blockbase = (int*)(ws + off);    off += 64 * 4;

    int nscan = (n_nodes + 1023) / 1024;   // 49 (must be <= 64)

    // 1) weight prep + zero counts
    wprep_kernel<<<384, 256, 0, stream>>>(W1, W2, W1t, W2t, counts, n_nodes);

    // 2) CSR build: hist -> 3-phase scan -> place
    hist_kernel<<<(n_edges + 255) / 256, 256, 0, stream>>>(edge_idx, counts, n_edges);
    scanA_kernel<<<nscan, 1024, 0, stream>>>(counts, offsets, blocksums, n_nodes);
    scanB_kernel<<<1, 64, 0, stream>>>(blocksums, blockbase, offsets, nscan, n_nodes);
    scanC_kernel<<<(n_nodes + 255) / 256, 256, 0, stream>>>(offsets, cursor, blockbase, n_nodes);
    place_kernel<<<(n_edges + 255) / 256, 256, 0, stream>>>(edge_idx, cursor, sorted_eid, n_edges);

    // 3) gather-sum + pack
    {
        int blocks = (n_nodes * 64 + 255) / 256;
        gather_kernel<<<blocks, 256, 0, stream>>>(edge_attr, sorted_eid, offsets, x, h_in, n_nodes);
    }

    // 4) GEMM1 + SiLU (m97 structure)
    {
        dim3 grid((n_nodes + 127) / 128, H_FEAT / 128);
        gemm1_kernel<<<grid, 256, 0, stream>>>(h_in, W1t, b1, act, n_nodes);
    }

    // 5) GEMM2 + LN + residual
    {
        int blocks = (n_nodes + 63) / 64;
        gemm2_ln_kernel<<<blocks, 256, 0, stream>>>(act, W2t, b2, gamma, beta, x, out, n_nodes);
    }
}